// Round 6
// baseline (5444.353 us; speedup 1.0000x reference)
//
#include <hip/hip_runtime.h>
#include <cstdint>

typedef short short8 __attribute__((ext_vector_type(8)));
typedef float floatx4 __attribute__((ext_vector_type(4)));

#define TS 512
#define BB 64
#define HD 1024
#define MROWS (TS * BB) // 32768

__device__ __forceinline__ unsigned short f2bf(float f) {
    uint32_t u = __float_as_uint(f);
    u += 0x7fffu + ((u >> 16) & 1u); // RNE
    return (unsigned short)(u >> 16);
}

__device__ __forceinline__ void wait_vm0() {
    asm volatile("s_waitcnt vmcnt(0)" ::: "memory");
}

// device-scope (MALL-direct) 16B load: bypasses L1/L2 so we need NO acquire
// fence / buffer_inv to see peer XCDs' sc1 write-through stores.
__device__ __forceinline__ void ld_sc1_b128(short8& d, const unsigned short* p) {
    asm volatile("global_load_dwordx4 %0, %1, off sc0 sc1"
                 : "=&v"(d) : "v"(p));
}

// counted wait for the inline-asm load pipeline + scheduler fence (rule #18:
// hipcc may hoist register-only MFMA past an asm waitcnt without the barrier)
#define VMWAIT(N)                                              \
    do {                                                       \
        asm volatile("s_waitcnt vmcnt(" #N ")" ::: "memory");  \
        __builtin_amdgcn_sched_barrier(0);                     \
    } while (0)

// ---------------- fp32 -> bf16 cast (vectorized) ----------------
__global__ __launch_bounds__(256) void cast_f32_bf16(const float* __restrict__ s,
                                                     unsigned short* __restrict__ d, int n4) {
    int i = blockIdx.x * 256 + threadIdx.x;
    if (i >= n4) return;
    float4 v = ((const float4*)s)[i];
    ushort4 o = make_ushort4(f2bf(v.x), f2bf(v.y), f2bf(v.z), f2bf(v.w));
    ((ushort4*)d)[i] = o;
}

// ---------------- input-projection GEMM (layer 0 only) ----------------
// C[M,2048] = A[M,K](bf16) * Bt[2048,K]^T + bias ; cols 0..1023 get biasF-1 (BETA), rest biasG
__global__ __launch_bounds__(256) void gemm_bt_bias(
    const unsigned short* __restrict__ A, const unsigned short* __restrict__ Bt,
    const float* __restrict__ biasF, const float* __restrict__ biasG,
    float* __restrict__ C, int M, int K)
{
    const int N = 2048;
    __shared__ unsigned short As[128 * 32];
    __shared__ unsigned short Bs[128 * 32];
    int bm = blockIdx.x * 128, bn = blockIdx.y * 128;
    int th = threadIdx.x;
    int wave = th >> 6, lane = th & 63;
    int lrow = lane & 15, quad = lane >> 4;
    int wm = (wave & 1) * 64, wn = (wave >> 1) * 64;
    const unsigned short* Ag = A + (size_t)bm * K;
    const unsigned short* Bg = Bt + (size_t)bn * K;

    floatx4 acc[4][4];
#pragma unroll
    for (int i = 0; i < 4; ++i)
#pragma unroll
        for (int j = 0; j < 4; ++j) acc[i][j] = (floatx4){0.f, 0.f, 0.f, 0.f};

    for (int k0 = 0; k0 < K; k0 += 32) {
        __syncthreads();
#pragma unroll
        for (int jj = 0; jj < 2; ++jj) {
            int c = jj * 256 + th;
            int row = c >> 2, kk = c & 3;
            int ph = (row * 4 + (kk ^ ((row >> 1) & 3))) * 8;
            uint4 va = *(const uint4*)(Ag + (size_t)row * K + k0 + kk * 8);
            uint4 vb = *(const uint4*)(Bg + (size_t)row * K + k0 + kk * 8);
            *(uint4*)(As + ph) = va;
            *(uint4*)(Bs + ph) = vb;
        }
        __syncthreads();
        short8 af[4], bfv[4];
#pragma unroll
        for (int i = 0; i < 4; ++i) {
            int r = wm + i * 16 + lrow;
            af[i] = *(const short8*)(As + (r * 4 + (quad ^ ((r >> 1) & 3))) * 8);
        }
#pragma unroll
        for (int j = 0; j < 4; ++j) {
            int r = wn + j * 16 + lrow;
            bfv[j] = *(const short8*)(Bs + (r * 4 + (quad ^ ((r >> 1) & 3))) * 8);
        }
#pragma unroll
        for (int i = 0; i < 4; ++i)
#pragma unroll
            for (int j = 0; j < 4; ++j)
                acc[i][j] = __builtin_amdgcn_mfma_f32_16x16x32_bf16(af[i], bfv[j], acc[i][j], 0, 0, 0);
    }
#pragma unroll
    for (int j = 0; j < 4; ++j) {
        int col = bn + wn + j * 16 + lrow;
        float bias = (col < 1024) ? (biasF[col] - 1.0f) : biasG[col - 1024];
#pragma unroll
        for (int i = 0; i < 4; ++i) {
            int row0 = bm + wm + i * 16 + quad * 4;
#pragma unroll
            for (int r = 0; r < 4; ++r)
                C[(size_t)(row0 + r) * N + col] = acc[i][j][r] + bias;
        }
    }
}

// ---------------- fused two-layer persistent JANET recurrence ----------------
// 128 WGs x 256 threads. WG w<64: layer0 cols [16w,16w+16). WG w>=64: layer1 cols.
// ring0 (8-deep) transports Y0 to layer1; layer1 computes Y0[t]@ifW1/igW1 on the fly.
// Sync protocol v6 (barrier-free, wave-granular):
//   Dataflow decomposes by wave index: producer (WG w, wave u) writes ring rows
//   [16u,16u+16); consumer wave v reads ONLY rows [16v,16v+16) -> consumer wave v
//   depends only on same-index producer waves. Flags are per-(WG,wave), one 128B
//   line each (256 lines / layer).
//   release (per wave, NO barrier): sc1 h-store drain (vmcnt0) -> lane0 sc1 flag.
//   acquire (per wave, NO barrier): each wave polls its 64 matched flags
//   (lane l -> flags[(l*4+wave)]), s_sleep backoff. NO acquire fence; ring reads
//   are global_load_dwordx4 sc0 sc1 (MALL-direct) pipelined with counted vmcnt.
//   L0 back-pressure on flags1 (ring0 slot reuse, 8-deep) amortized: checked when
//   t%4==1 with threshold t-4 (covers steps t..t+3; step t' needs flags1>=t'-7).
// L1's poll (flags0>=t+1, flags1>=t) implies its ring reuse safety (2-deep ring1,
// wave-matched rows only).
__global__ __launch_bounds__(256) void janet_fused(
    const float* __restrict__ P,            // layer0 [T*64, 2048] (pf|pg), ifB0-BETA folded
    const unsigned short* __restrict__ Rf0, const unsigned short* __restrict__ Rg0,
    const float* __restrict__ hbf0, const float* __restrict__ hbg0,
    const unsigned short* __restrict__ Rf1, const unsigned short* __restrict__ Rg1,
    const unsigned short* __restrict__ Wi1, // [2048,1024] bf16: ifW1 rows then igW1 rows
    const float* __restrict__ ifB1, const float* __restrict__ hfB1,
    const float* __restrict__ igB1, const float* __restrict__ hgB1,
    unsigned short* __restrict__ ring0,     // [8][64][1024] bf16, zeroed
    unsigned short* __restrict__ ring1,     // [2][64][1024] bf16, zeroed
    int* flags0, int* flags1,               // [64*4*32] each: one 128B line per (WG,wave)
    float* __restrict__ Yf32)               // layer1 output fp32 [T,64,1024]
{
    __shared__ unsigned short Wl[4][16 * 1024]; // 128 KiB (L0 uses slices 0,1 only)
    const int wg = blockIdx.x, th = threadIdx.x;
    const bool L1 = wg >= 64;
    const int w = L1 ? (wg - 64) : wg;
    const int wave = th >> 6, lane = th & 63;
    const int lrow = lane & 15, quad = lane >> 4;
    const int c0 = w * 16;
    const int col = c0 + lrow;
    const int myrow = wave * 16 + lrow;
    const int sw = lrow & 7;

    // load weight slices once (XOR-swizzled by (n&7) on 8-elem chunks)
    const int nchunks = L1 ? 8192 : 4096;
    for (int c = th; c < nchunks; c += 256) {
        int g = c >> 11, n = (c >> 7) & 15, k8 = c & 127;
        const unsigned short* src;
        if (L1) src = (g == 0) ? Rf1 : (g == 1) ? Rg1 : (g == 2) ? Wi1 : (Wi1 + (size_t)1024 * 1024);
        else    src = g ? Rg0 : Rf0;
        src += (size_t)(c0 + n) * 1024 + k8 * 8;
        *(uint4*)(&Wl[g][(n * 128 + (k8 ^ (n & 7))) * 8]) = *(const uint4*)src;
    }
    __syncthreads();

    float bF, bG;
    if (L1) { bF = ifB1[col] - 1.0f + hfB1[col]; bG = igB1[col] + hgB1[col]; }
    else    { bF = hbf0[col]; bG = hbg0[col]; }

    const unsigned short* w0 = &Wl[0][lrow << 10];
    const unsigned short* w1 = &Wl[1][lrow << 10];
    const unsigned short* w2 = &Wl[2][lrow << 10];
    const unsigned short* w3 = &Wl[3][lrow << 10];

    float hr[4] = {0.f, 0.f, 0.f, 0.f}; // fp32 master h (b = wave*16+quad*4+r)

    // per-(WG,wave) flag index: lane l covers producer WG l (matched wave)
    const int fpoll = ((lane << 2) | wave) << 5;
    const int fmine = ((w << 2) | wave) << 5;

    // acquire: every wave polls its own 64 matched flags; no barrier, no fence
    auto pollWV = [&](int th0_, int th1_, bool useBP) {
        int spins = 0;
        while (true) {
            int f0 = __hip_atomic_load(&flags0[fpoll], __ATOMIC_RELAXED,
                                       __HIP_MEMORY_SCOPE_AGENT);
            bool ok = f0 >= th0_;
            if (useBP) {
                int f1 = __hip_atomic_load(&flags1[fpoll], __ATOMIC_RELAXED,
                                           __HIP_MEMORY_SCOPE_AGENT);
                ok = ok && (f1 >= th1_);
            }
            if (__all(ok)) break;
            if (++spins > (1 << 20)) break; // bail loudly rather than hang
            if (spins > 4) __builtin_amdgcn_s_sleep(1);
        }
    };

    // release (per wave): drain own sc1 stores, then lane0 fires this wave's flag
    auto release = [&](int* flags, int v) {
        wait_vm0();
        if (lane == 0)
            __hip_atomic_store(&flags[fmine], v, __ATOMIC_RELAXED, __HIP_MEMORY_SCOPE_AGENT);
    };

    if (!L1) {
        // ---------------- layer 0 ----------------
        float pf[4], pg[4];
        auto pload = [&](int t, float* pfD, float* pgD) {
            size_t pbase = ((size_t)t * 64 + wave * 16 + quad * 4) * 2048 + col;
#pragma unroll
            for (int r = 0; r < 4; ++r) {
                pfD[r] = P[pbase + (size_t)r * 2048];
                pgD[r] = P[pbase + (size_t)r * 2048 + 1024];
            }
        };
        pload(0, pf, pg);

        for (int t = 0; t < TS; ++t) {
            // same-wave peers stored h0[t]; flags1 back-pressure amortized
            if (t) pollWV(t, t - 4, (t & 3) == 1);

            const unsigned short* hs =
                ring0 + ((size_t)(t & 7) << 16) + ((size_t)myrow << 10) + (quad << 3);

            wait_vm0(); // clean vm counter for counted waits
            short8 hA[8], hB[8];
            auto issue = [&](int c, short8* buf) {
#pragma unroll
                for (int i = 0; i < 8; ++i)
                    ld_sc1_b128(buf[i], hs + (((c << 3) + i) << 5));
            };
            floatx4 aF = {0.f, 0.f, 0.f, 0.f}, aG = {0.f, 0.f, 0.f, 0.f};
            auto mchunk = [&](int c, const short8* buf) {
#pragma unroll
                for (int i = 0; i < 8; ++i) {
                    int ks = (c << 3) + i;
                    int koff = ((((ks << 2) + quad) ^ sw) << 3);
                    short8 bf_ = *(const short8*)(w0 + koff);
                    short8 bg_ = *(const short8*)(w1 + koff);
                    aF = __builtin_amdgcn_mfma_f32_16x16x32_bf16(buf[i], bf_, aF, 0, 0, 0);
                    aG = __builtin_amdgcn_mfma_f32_16x16x32_bf16(buf[i], bg_, aG, 0, 0, 0);
                }
            };
            issue(0, hA);
            issue(1, hB);
            VMWAIT(8); mchunk(0, hA); issue(2, hA);
            VMWAIT(8); mchunk(1, hB); issue(3, hB);
            VMWAIT(8); mchunk(2, hA);
            VMWAIT(0); mchunk(3, hB);

            unsigned short* hd = ring0 + ((size_t)((t + 1) & 7) << 16);
#pragma unroll
            for (int r = 0; r < 4; ++r) {
                int b = wave * 16 + quad * 4 + r;
                float f = 1.f / (1.f + __expf(-(pf[r] + aF[r] + bF)));
                float xg = pg[r] + aG[r] + bG;
                xg = fminf(fmaxf(xg, -15.f), 15.f);
                float e2 = __expf(2.f * xg);
                float g = (e2 - 1.f) / (e2 + 1.f);
                float hn = f * hr[r] + (1.f - f) * g;
                hr[r] = hn;
                unsigned short hb = f2bf(hn);
                int partner = __shfl_xor((int)hb, 1, 64);
                if (!(lrow & 1)) {
                    unsigned int pk = (unsigned int)hb | ((unsigned int)partner << 16);
                    __hip_atomic_store((unsigned int*)(hd + (size_t)b * 1024 + col), pk,
                                       __ATOMIC_RELAXED, __HIP_MEMORY_SCOPE_AGENT);
                }
            }
            release(flags0, t + 1);
            if (t + 1 < TS) pload(t + 1, pf, pg); // flies during next poll
        }
    } else {
        // ---------------- layer 1 ----------------
        for (int t = 0; t < TS; ++t) {
            pollWV(t + 1, t, true); // Y0[t] published; same-wave peers stored h1[t]

            const unsigned short* ys =
                ring0 + ((size_t)((t + 1) & 7) << 16) + ((size_t)myrow << 10) + (quad << 3);
            const unsigned short* hs =
                ring1 + ((size_t)(t & 1) << 16) + ((size_t)myrow << 10) + (quad << 3);

            wait_vm0(); // clean vm counter for counted waits
            short8 yA[4], yB[4], hA[4], hB[4];
            auto lcI = [&](int c, short8* yb, short8* hb) {
#pragma unroll
                for (int i = 0; i < 4; ++i) {
                    ld_sc1_b128(yb[i], ys + (((c << 2) + i) << 5));
                    ld_sc1_b128(hb[i], hs + (((c << 2) + i) << 5));
                }
            };
            floatx4 aPf = {0.f, 0.f, 0.f, 0.f}, aPg = {0.f, 0.f, 0.f, 0.f};
            floatx4 aF = {0.f, 0.f, 0.f, 0.f},  aG = {0.f, 0.f, 0.f, 0.f};
            auto mc = [&](int c, const short8* yb, const short8* hb) {
#pragma unroll
                for (int i = 0; i < 4; ++i) {
                    int ks = (c << 2) + i;
                    int koff = ((((ks << 2) + quad) ^ sw) << 3);
                    short8 wf_ = *(const short8*)(w0 + koff);
                    short8 wg_ = *(const short8*)(w1 + koff);
                    short8 wif = *(const short8*)(w2 + koff);
                    short8 wig = *(const short8*)(w3 + koff);
                    aF  = __builtin_amdgcn_mfma_f32_16x16x32_bf16(hb[i], wf_, aF, 0, 0, 0);
                    aG  = __builtin_amdgcn_mfma_f32_16x16x32_bf16(hb[i], wg_, aG, 0, 0, 0);
                    aPf = __builtin_amdgcn_mfma_f32_16x16x32_bf16(yb[i], wif, aPf, 0, 0, 0);
                    aPg = __builtin_amdgcn_mfma_f32_16x16x32_bf16(yb[i], wig, aPg, 0, 0, 0);
                }
            };
            lcI(0, yA, hA);
            lcI(1, yB, hB);
            VMWAIT(8); mc(0, yA, hA); lcI(2, yA, hA);
            VMWAIT(8); mc(1, yB, hB); lcI(3, yB, hB);
            VMWAIT(8); mc(2, yA, hA); lcI(4, yA, hA);
            VMWAIT(8); mc(3, yB, hB); lcI(5, yB, hB);
            VMWAIT(8); mc(4, yA, hA); lcI(6, yA, hA);
            VMWAIT(8); mc(5, yB, hB); lcI(7, yB, hB);
            VMWAIT(8); mc(6, yA, hA);
            VMWAIT(0); mc(7, yB, hB);

            unsigned short* hd = ring1 + ((size_t)((t + 1) & 1) << 16);
#pragma unroll
            for (int r = 0; r < 4; ++r) {
                int b = wave * 16 + quad * 4 + r;
                float f = 1.f / (1.f + __expf(-(aPf[r] + aF[r] + bF)));
                float xg = aPg[r] + aG[r] + bG;
                xg = fminf(fmaxf(xg, -15.f), 15.f);
                float e2 = __expf(2.f * xg);
                float g = (e2 - 1.f) / (e2 + 1.f);
                float hn = f * hr[r] + (1.f - f) * g;
                hr[r] = hn;
                unsigned short hb = f2bf(hn);
                int partner = __shfl_xor((int)hb, 1, 64);
                if (!(lrow & 1)) {
                    unsigned int pk = (unsigned int)hb | ((unsigned int)partner << 16);
                    __hip_atomic_store((unsigned int*)(hd + (size_t)b * 1024 + col), pk,
                                       __ATOMIC_RELAXED, __HIP_MEMORY_SCOPE_AGENT);
                }
                // plain L2 store, included in the drain window (cheap) so it
                // cannot pollute the next step's poll wait
                Yf32[((size_t)t * 64 + b) * 1024 + col] = hn;
            }
            release(flags1, t + 1);
        }
    }
}

extern "C" void kernel_launch(void* const* d_in, const int* in_sizes, int n_in,
                              void* d_out, int out_size, void* d_ws, size_t ws_size,
                              hipStream_t stream) {
    (void)in_sizes; (void)n_in; (void)out_size; (void)ws_size;
    const float* X    = (const float*)d_in[0];
    const float* ifW0 = (const float*)d_in[1];
    const float* ifB0 = (const float*)d_in[2];
    const float* hfW0 = (const float*)d_in[3];
    const float* hfB0 = (const float*)d_in[4];
    const float* igW0 = (const float*)d_in[5];
    const float* igB0 = (const float*)d_in[6];
    const float* hgW0 = (const float*)d_in[7];
    const float* hgB0 = (const float*)d_in[8];
    const float* ifW1 = (const float*)d_in[9];
    const float* ifB1 = (const float*)d_in[10];
    const float* hfW1 = (const float*)d_in[11];
    const float* hfB1 = (const float*)d_in[12];
    const float* igW1 = (const float*)d_in[13];
    const float* igB1 = (const float*)d_in[14];
    const float* hgW1 = (const float*)d_in[15];
    const float* hgB1 = (const float*)d_in[16];

    char* p = (char*)d_ws;
    auto alloc = [&](size_t bytes) {
        char* r = p; p += (bytes + 255) & ~(size_t)255; return r;
    };
    float* P            = (float*)alloc((size_t)MROWS * 2048 * 4);          // 256 MB
    unsigned short* Xb  = (unsigned short*)alloc((size_t)MROWS * 512 * 2);  // 32 MB
    unsigned short* W0c = (unsigned short*)alloc((size_t)2048 * 512 * 2);   // GEMM weights L0
    unsigned short* W1c = (unsigned short*)alloc((size_t)2048 * 1024 * 2);  // ifW1|igW1 bf16
    unsigned short* Rf0 = (unsigned short*)alloc((size_t)1024 * 1024 * 2);
    unsigned short* Rg0 = (unsigned short*)alloc((size_t)1024 * 1024 * 2);
    unsigned short* Rf1 = (unsigned short*)alloc((size_t)1024 * 1024 * 2);
    unsigned short* Rg1 = (unsigned short*)alloc((size_t)1024 * 1024 * 2);
    // contiguous zero-init region: ring0 | ring1 | flags0 | flags1 (per-wave padded)
    unsigned short* ring0 = (unsigned short*)alloc((size_t)8 * 64 * 1024 * 2); // 1 MB
    unsigned short* ring1 = (unsigned short*)alloc((size_t)2 * 64 * 1024 * 2); // 256 KB
    int* flags0 = (int*)alloc(256 * 32 * 4); // 32 KB: one 128B line per (WG,wave)
    int* flags1 = (int*)alloc(256 * 32 * 4); // 32 KB

    // ws is poisoned every call: zero rings + flags in one memset
    hipMemsetAsync(ring0, 0, (size_t)1048576 + 262144 + 32768 + 32768, stream);

    auto cast = [&](const float* s, unsigned short* d, size_t n) {
        int n4 = (int)(n / 4);
        cast_f32_bf16<<<dim3((n4 + 255) / 256), dim3(256), 0, stream>>>(s, d, n4);
    };
    cast(X, Xb, (size_t)MROWS * 512);
    cast(ifW0, W0c, (size_t)1024 * 512);
    cast(igW0, W0c + (size_t)1024 * 512, (size_t)1024 * 512);
    cast(ifW1, W1c, (size_t)1024 * 1024);
    cast(igW1, W1c + (size_t)1024 * 1024, (size_t)1024 * 1024);
    cast(hfW0, Rf0, (size_t)1024 * 1024);
    cast(hgW0, Rg0, (size_t)1024 * 1024);
    cast(hfW1, Rf1, (size_t)1024 * 1024);
    cast(hgW1, Rg1, (size_t)1024 * 1024);

    // layer-0 input projections (layer 1's are computed on the fly in the fused kernel)
    gemm_bt_bias<<<dim3(MROWS / 128, 16), dim3(256), 0, stream>>>(Xb, W0c, ifB0, igB0, P, MROWS, 512);

    // fused two-layer pipelined scan: 64 WGs layer0 + 64 WGs layer1, 1-step skew
    janet_fused<<<dim3(128), dim3(256), 0, stream>>>(
        P, Rf0, Rg0, hfB0, hgB0,
        Rf1, Rg1, W1c, ifB1, hfB1, igB1, hgB1,
        ring0, ring1, flags0, flags1, (float*)d_out);
}